// Round 1
// baseline (1620.377 us; speedup 1.0000x reference)
//
#include <hip/hip_runtime.h>
#include <hip/hip_bf16.h>
#include <math.h>
#include <stdint.h>

#define N_TOK 1048576
#define BSEG  4096
#define DIM   256
#define HID   128
#define TPC   32                       // tokens per chunk
#define CPB   64                       // chunks per block
#define GRID  (N_TOK / (TPC * CPB))    // 512 blocks, persistent (2/CU)

typedef __attribute__((ext_vector_type(8))) short short8;
typedef __attribute__((ext_vector_type(4))) float f32x4;

__device__ __forceinline__ short f2bf(float f) {
    union { float f; unsigned u; } v; v.f = f;
    unsigned r = v.u + 0x7fff + ((v.u >> 16) & 1);   // RNE
    return (short)(r >> 16);
}

// tanh(x) = 1 - 2/(1+e^{2x}); v_exp-based, saturates correctly at +-inf
__device__ __forceinline__ float fast_tanh(float v) {
    float e = __expf(2.f * v);
    return 1.f - __fdividef(2.f, e + 1.f);
}

typedef __attribute__((address_space(1))) const unsigned int as1_u32;
typedef __attribute__((address_space(3))) unsigned int as3_u32;
// async 16B global->LDS DMA; lds base is wave-uniform, HW adds lane*16
__device__ __forceinline__ void gload16(const void* g, void* l) {
    __builtin_amdgcn_global_load_lds((as1_u32*)g, (as3_u32*)l, 16, 0, 0);
}

// raw barriers: do NOT drain vmcnt (keeps the global_load_lds pipeline alive)
#define BAR_LGKM() do { asm volatile("s_waitcnt lgkmcnt(0)" ::: "memory"); \
    __builtin_amdgcn_s_barrier(); asm volatile("" ::: "memory"); } while (0)
#define BAR_ALL() do { asm volatile("s_waitcnt vmcnt(0) lgkmcnt(0)" ::: "memory"); \
    __builtin_amdgcn_s_barrier(); asm volatile("" ::: "memory"); } while (0)

// ---- prep: W1 [D][H] fp32 -> W1T [H][D] bf16 (k-contiguous rows) ----
__global__ void prep_w1t(const float* __restrict__ W1, short* __restrict__ W1T) {
    int i = blockIdx.x * blockDim.x + threadIdx.x;   // 0..32767
    int h = i >> 8;        // row of W1T
    int k = i & 255;       // col of W1T (= row of W1)
    W1T[i] = f2bf(W1[k * HID + h]);
}

// ---- fused main: async-pipelined chunks of 32 tokens ----
__launch_bounds__(256, 2)
__global__ void main_kernel(const float* __restrict__ x,
                            const int*  __restrict__ seg,
                            const short* __restrict__ W1T,
                            const float* __restrict__ b1,
                            const float* __restrict__ W2,
                            const float* __restrict__ b2,
                            float* __restrict__ ctx,     // d_out[0 .. B*D)
                            float* __restrict__ zout,    // d_out + B*D
                            float* __restrict__ denom) {
    // fp32 x tiles, double-buffered; physical byte = logical ^ ((row&7)<<4)
    // (swizzle applied on the GLOBAL source so the linear-dest DMA matches)
    __shared__ __align__(16) float x_lds[2][TPC * DIM];  // 2 x 32 KiB
    __shared__ __align__(16) int   seg_all[TPC * CPB];   // 8 KiB, whole block
    __shared__ float s_part[4][TPC];
    __shared__ float z_lds[TPC];

    const int tid  = threadIdx.x;
    const int wv   = tid >> 6;        // wave 0..3
    const int lane = tid & 63;
    const int q    = lane >> 4;       // quad 0..3
    const int c    = lane & 15;       // col 0..15
    const long tok0 = (long)blockIdx.x * (TPC * CPB);

    char* xb0 = (char*)&x_lds[0][0];
    char* xb1 = (char*)&x_lds[1][0];
    const int drb = wv * 1024 + lane * 16;

    // ---- prologue: stage chunk 0 + all segment ids (async DMA) ----
    {
        const char* g = (const char*)(x + tok0 * DIM);
#pragma unroll
        for (int i = 0; i < 8; ++i) {
            int dr = drb + i * 4096;
            int sr = dr ^ (((dr >> 10) & 7) << 4);
            gload16(g + sr, xb0 + i * 4096 + wv * 1024);
        }
        const char* sg = (const char*)(seg + tok0);
        char* sb = (char*)seg_all;
#pragma unroll
        for (int i = 0; i < 2; ++i)
            gload16(sg + i * 4096 + drb, sb + i * 4096 + wv * 1024);
    }

    // preload this wave's W1T B-fragments (hidden tiles wv, wv+4): 64 VGPRs
    short8 bf[2][8];
#pragma unroll
    for (int ti = 0; ti < 2; ++ti) {
        int t = wv + 4 * ti;
#pragma unroll
        for (int kk = 0; kk < 8; ++kk)
            bf[ti][kk] = *reinterpret_cast<const short8*>(
                W1T + (t * 16 + c) * 256 + kk * 32 + q * 8);
    }
    const float b1v0 = b1[wv * 16 + c];
    const float b1v1 = b1[(wv + 4) * 16 + c];
    const float w2v0 = W2[wv * 16 + c];
    const float w2v1 = W2[(wv + 4) * 16 + c];
    const float b2s  = b2[0];

    // persistent pooling state (tokens are contiguous per block)
    float pool_acc = 0.f;
    int   prev  = seg[tok0];
    float az    = 0.f;
    int   prevd = prev;

    BAR_ALL();   // chunk 0 + seg_all + frags resident

    for (int ci = 0; ci < CPB; ++ci) {
        char* cur = (ci & 1) ? xb1 : xb0;
        // issue next chunk's DMA first; it flies under the whole compute phase
        if (ci + 1 < CPB) {
            const char* g = (const char*)(x + (tok0 + (long)(ci + 1) * TPC) * DIM);
            char* nb = (ci & 1) ? xb0 : xb1;
#pragma unroll
            for (int i = 0; i < 8; ++i) {
                int dr = drb + i * 4096;
                int sr = dr ^ (((dr >> 10) & 7) << 4);
                gload16(g + sr, nb + i * 4096 + wv * 1024);
            }
        }

        // ---- logits: MFMA over staged fp32, bf16 convert at fragment read ----
#pragma unroll
        for (int tt = 0; tt < 2; ++tt) {
            f32x4 acc0 = {0.f, 0.f, 0.f, 0.f};
            f32x4 acc1 = {0.f, 0.f, 0.f, 0.f};
            const int row = tt * 16 + c;
            const char* p0 = cur + row * 1024 + ((q * 32) ^ ((c & 7) << 4));
            const char* p1 = (const char*)((uintptr_t)p0 ^ 16u);
#pragma unroll
            for (int kk = 0; kk < 8; ++kk) {
                f32x4 v0 = *(const f32x4*)(p0 + kk * 128);
                f32x4 v1 = *(const f32x4*)(p1 + kk * 128);
                short8 a = { f2bf(v0[0]), f2bf(v0[1]), f2bf(v0[2]), f2bf(v0[3]),
                             f2bf(v1[0]), f2bf(v1[1]), f2bf(v1[2]), f2bf(v1[3]) };
                acc0 = __builtin_amdgcn_mfma_f32_16x16x32_bf16(a, bf[0][kk], acc0, 0, 0, 0);
                acc1 = __builtin_amdgcn_mfma_f32_16x16x32_bf16(a, bf[1][kk], acc1, 0, 0, 0);
            }
            float part[4];
#pragma unroll
            for (int r = 0; r < 4; ++r) {
                float h0 = fast_tanh(acc0[r] + b1v0);
                float h1 = fast_tanh(acc1[r] + b1v1);
                part[r] = h0 * w2v0 + h1 * w2v1;
            }
#pragma unroll
            for (int r = 0; r < 4; ++r) {           // sum over 16 hidden cols
                float v = part[r];
                v += __shfl_xor(v, 1);
                v += __shfl_xor(v, 2);
                v += __shfl_xor(v, 4);
                v += __shfl_xor(v, 8);
                part[r] = v;
            }
            if (c == 0)
                *reinterpret_cast<float4*>(&s_part[wv][tt * 16 + q * 4]) =
                    make_float4(part[0], part[1], part[2], part[3]);
        }
        BAR_LGKM();

        // ---- combine wave partials -> s -> z = exp(s) ----
        if (tid < TPC) {
            float s = s_part[0][tid] + s_part[1][tid] + s_part[2][tid]
                    + s_part[3][tid] + b2s;
            float z = __expf(s);
            z_lds[tid] = z;
            zout[tok0 + (long)ci * TPC + tid] = z;   // normalized by finalize
        }
        BAR_LGKM();

        // ---- pooling: thread j owns feature j; flush on segment change ----
        {
            const int* sgl = &seg_all[ci * TPC];
            const int j4 = tid * 4;
#pragma unroll 8
            for (int n = 0; n < TPC; ++n) {
                int s = sgl[n];
                float xv = *(const float*)(cur + n * 1024 + (j4 ^ ((n & 7) << 4)));
                if (s != prev) {
                    atomicAdd(&ctx[(long)prev * DIM + tid], pool_acc);
                    pool_acc = 0.f;
                    prev = s;
                }
                pool_acc += z_lds[n] * xv;
            }
        }
        if (tid == 0) {
            const int* sgl = &seg_all[ci * TPC];
            for (int n = 0; n < TPC; ++n) {
                int s = sgl[n];
                if (s != prevd) { atomicAdd(&denom[prevd], az); az = 0.f; prevd = s; }
                az += z_lds[n];
            }
        }
        // next chunk staged + all LDS reads of 'cur' retired -> safe to swap
        BAR_ALL();
    }
    atomicAdd(&ctx[(long)prev * DIM + tid], pool_acc);
    if (tid == 0) atomicAdd(&denom[prevd], az);
}

// ---- finalize: normalize context rows and attention weights in place ----
__global__ void finalize(float* __restrict__ out, const float* __restrict__ denom,
                         const int* __restrict__ seg) {
    long idx = (long)blockIdx.x * 256 + threadIdx.x;
    const long BD = (long)BSEG * DIM;
    if (idx < BD) {
        float dn = denom[idx >> 8];
        float v = out[idx];
        out[idx] = dn > 0.f ? v / dn : 0.f;
    } else {
        long n = idx - BD;
        float dn = denom[seg[n]];
        float z = out[idx];
        out[idx] = dn > 0.f ? z / dn : 0.f;
    }
}

extern "C" void kernel_launch(void* const* d_in, const int* in_sizes, int n_in,
                              void* d_out, int out_size, void* d_ws, size_t ws_size,
                              hipStream_t stream) {
    const float* x  = (const float*)d_in[0];
    const int*   sg = (const int*)d_in[1];
    const float* W1 = (const float*)d_in[2];
    const float* b1 = (const float*)d_in[3];
    const float* W2 = (const float*)d_in[4];
    const float* b2 = (const float*)d_in[5];
    float* out = (float*)d_out;

    short* W1T   = (short*)d_ws;                       // 64 KiB
    float* denom = (float*)((char*)d_ws + 65536);      // 16 KiB
    const long BD = (long)BSEG * DIM;

    hipMemsetAsync(out, 0, BD * sizeof(float), stream);        // ctx accumulators
    hipMemsetAsync(denom, 0, BSEG * sizeof(float), stream);

    prep_w1t<<<(HID * DIM) / 256, 256, 0, stream>>>(W1, W1T);
    main_kernel<<<GRID, 256, 0, stream>>>(x, sg, W1T, b1, W2, b2,
                                          out, out + BD, denom);
    finalize<<<(int)((BD + N_TOK) / 256), 256, 0, stream>>>(out, denom, sg);
}

// Round 2
// 1392.399 us; speedup vs baseline: 1.1637x; 1.1637x over previous
//
#include <hip/hip_runtime.h>
#include <hip/hip_bf16.h>
#include <math.h>

#define N_TOK 1048576
#define BSEG  4096
#define DIM   256
#define HID   128

typedef __attribute__((ext_vector_type(8))) short short8;
typedef __attribute__((ext_vector_type(4))) short short4v;
typedef __attribute__((ext_vector_type(4))) float f32x4;

__device__ __forceinline__ short f2bf(float f) {
    union { float f; unsigned u; } v; v.f = f;
    unsigned r = v.u + 0x7fff + ((v.u >> 16) & 1);   // RNE
    return (short)(r >> 16);
}
__device__ __forceinline__ float bf2f(short s) {
    union { unsigned u; float f; } v;
    v.u = ((unsigned)(unsigned short)s) << 16;
    return v.f;
}

// tanh(x) = 1 - 2/(1+e^{2x}); v_exp-based (~5 VALU ops), saturates at +-inf.
// |err| ~1e-7 relative -- invisible under the bf16 matmul error (2^-9 absmax).
__device__ __forceinline__ float fast_tanh(float v) {
    float e = __expf(2.f * v);
    return 1.f - __fdividef(2.f, e + 1.f);
}

// ---- prep: W1 [D][H] fp32 -> W1T [H][D] bf16 (k-contiguous rows) ----
__global__ void prep_w1t(const float* __restrict__ W1, short* __restrict__ W1T) {
    int i = blockIdx.x * blockDim.x + threadIdx.x;   // 0..32767
    int h = i >> 8;        // row of W1T
    int k = i & 255;       // col of W1T (= row of W1)
    W1T[i] = f2bf(W1[k * HID + h]);
}

// ---- fused main: logits (MFMA) -> z=exp(s) -> unnormalized pooling ----
// 4 blocks/CU (LDS 35.3 KB x 4 = 141 KB); 16 waves/CU for stage/compute overlap.
__launch_bounds__(256, 4)
__global__ void main_kernel(const float* __restrict__ x,
                            const int*  __restrict__ seg,
                            const short* __restrict__ W1T,
                            const float* __restrict__ b1,
                            const float* __restrict__ W2,
                            const float* __restrict__ b2,
                            float* __restrict__ ctx,     // d_out[0 .. B*D)
                            float* __restrict__ zout,    // d_out + B*D
                            float* __restrict__ denom) {
    // LDS: 64 tokens x 256 k bf16, row stride 264 shorts (528 B): conflict-free
    __shared__ __align__(16) short x_lds[64 * 264];      // 33792 B
    __shared__ float s_part[4][64];
    __shared__ float z_lds[64];
    __shared__ int   seg_lds[64];

    const int tid  = threadIdx.x;
    const int wv   = tid >> 6;        // wave 0..3
    const int lane = tid & 63;
    const int q    = lane >> 4;       // quad 0..3
    const int c    = lane & 15;       // col 0..15
    const long base_tok = (long)blockIdx.x * 64;

    if (tid < 64) seg_lds[tid] = seg[base_tok + tid];

    // stage x chunk -> LDS bf16, coalesced float4 loads (one wave per token row)
    const float4* xg = reinterpret_cast<const float4*>(x) + base_tok * 64;
#pragma unroll
    for (int it = 0; it < 16; ++it) {
        int flat  = it * 256 + tid;
        int token = flat >> 6, kq = flat & 63;
        float4 v = xg[flat];
        short4v p = { f2bf(v.x), f2bf(v.y), f2bf(v.z), f2bf(v.w) };
        *reinterpret_cast<short4v*>(&x_lds[token * 264 + kq * 4]) = p;
    }

    // preload this wave's W1T B-fragments (hidden tiles wv and wv+4), 64 VGPRs
    short8 bf[2][8];
#pragma unroll
    for (int ti = 0; ti < 2; ++ti) {
        int t = wv + 4 * ti;
#pragma unroll
        for (int kk = 0; kk < 8; ++kk) {
            bf[ti][kk] = *reinterpret_cast<const short8*>(
                W1T + (t * 16 + c) * 256 + kk * 32 + q * 8);
        }
    }
    const float b1v0 = b1[wv * 16 + c];
    const float b1v1 = b1[(wv + 4) * 16 + c];
    const float w2v0 = W2[wv * 16 + c];
    const float w2v1 = W2[(wv + 4) * 16 + c];
    const float b2s  = b2[0];

    __syncthreads();

    // 4 token-tiles of 16; each wave does all tokens x its 32 hidden
#pragma unroll
    for (int tt = 0; tt < 4; ++tt) {
        f32x4 acc0 = {0.f, 0.f, 0.f, 0.f};
        f32x4 acc1 = {0.f, 0.f, 0.f, 0.f};
        const short* arow = &x_lds[(tt * 16 + c) * 264 + q * 8];
#pragma unroll
        for (int kk = 0; kk < 8; ++kk) {
            short8 a = *reinterpret_cast<const short8*>(arow + kk * 32);
            acc0 = __builtin_amdgcn_mfma_f32_16x16x32_bf16(a, bf[0][kk], acc0, 0, 0, 0);
            acc1 = __builtin_amdgcn_mfma_f32_16x16x32_bf16(a, bf[1][kk], acc1, 0, 0, 0);
        }
        // tanh + W2 partial dot (this wave's 32 hidden), then reduce over 16 cols
        float part[4];
#pragma unroll
        for (int r = 0; r < 4; ++r) {
            float h0 = fast_tanh(acc0[r] + b1v0);
            float h1 = fast_tanh(acc1[r] + b1v1);
            part[r] = h0 * w2v0 + h1 * w2v1;
        }
#pragma unroll
        for (int r = 0; r < 4; ++r) {
            float v = part[r];
            v += __shfl_xor(v, 1);
            v += __shfl_xor(v, 2);
            v += __shfl_xor(v, 4);
            v += __shfl_xor(v, 8);
            part[r] = v;
        }
        if (c == 0) {
            float4 st = make_float4(part[0], part[1], part[2], part[3]);
            *reinterpret_cast<float4*>(&s_part[wv][tt * 16 + q * 4]) = st;
        }
    }
    __syncthreads();

    // combine wave partials -> s -> z = exp(s); denom via wave-parallel
    // segmented scan (segment ids are sorted => contiguous runs)
    if (tid < 64) {
        float s = s_part[0][tid] + s_part[1][tid] + s_part[2][tid] + s_part[3][tid] + b2s;
        float z = expf(s);
        z_lds[tid] = z;
        zout[base_tok + tid] = z;             // normalized later

        int   sg = seg_lds[tid];
        float v  = z;
#pragma unroll
        for (int d = 1; d < 64; d <<= 1) {
            float vu = __shfl_up(v, d);
            int   su = __shfl_up(sg, d);
            if (tid >= d && su == sg) v += vu;   // valid: runs are contiguous
        }
        bool last = (tid == 63) || (seg_lds[tid + 1] != sg);
        if (last) atomicAdd(&denom[sg], v);
    }
    __syncthreads();

    // pooling: thread j owns feature d=j; walk tokens, flush on segment boundary
    {
        const int j = tid;
        float acc = 0.f;
        int prev = seg_lds[0];
#pragma unroll 4
        for (int n = 0; n < 64; ++n) {
            int sg = seg_lds[n];
            if (sg != prev) {                     // wave-uniform branch
                atomicAdd(&ctx[(long)prev * DIM + j], acc);
                acc = 0.f;
                prev = sg;
            }
            acc += z_lds[n] * bf2f(x_lds[n * 264 + j]);
        }
        atomicAdd(&ctx[(long)prev * DIM + j], acc);
    }
}

// ---- finalize: normalize context rows and attention weights in place ----
__global__ void finalize(float* __restrict__ out, const float* __restrict__ denom,
                         const int* __restrict__ seg) {
    long idx = (long)blockIdx.x * 256 + threadIdx.x;
    const long BD = (long)BSEG * DIM;
    if (idx < BD) {
        float dn = denom[idx >> 8];
        float v = out[idx];
        out[idx] = dn > 0.f ? v / dn : 0.f;
    } else {
        long n = idx - BD;
        float dn = denom[seg[n]];
        float z = out[idx];
        out[idx] = dn > 0.f ? z / dn : 0.f;
    }
}

extern "C" void kernel_launch(void* const* d_in, const int* in_sizes, int n_in,
                              void* d_out, int out_size, void* d_ws, size_t ws_size,
                              hipStream_t stream) {
    const float* x  = (const float*)d_in[0];
    const int*   sg = (const int*)d_in[1];
    const float* W1 = (const float*)d_in[2];
    const float* b1 = (const float*)d_in[3];
    const float* W2 = (const float*)d_in[4];
    const float* b2 = (const float*)d_in[5];
    float* out = (float*)d_out;

    short* W1T   = (short*)d_ws;                       // 64 KiB
    float* denom = (float*)((char*)d_ws + 65536);      // 16 KiB
    const long BD = (long)BSEG * DIM;

    hipMemsetAsync(out, 0, BD * sizeof(float), stream);        // ctx accumulators
    hipMemsetAsync(denom, 0, BSEG * sizeof(float), stream);

    prep_w1t<<<(HID * DIM) / 256, 256, 0, stream>>>(W1, W1T);
    main_kernel<<<N_TOK / 64, 256, 0, stream>>>(x, sg, W1T, b1, W2, b2,
                                                out, out + BD, denom);
    finalize<<<(int)((BD + N_TOK) / 256), 256, 0, stream>>>(out, denom, sg);
}